// Round 4
// baseline (342.470 us; speedup 1.0000x reference)
//
#include <hip/hip_runtime.h>
#include <hip/hip_bf16.h>

#define NN 100000
#define NE 1600000
#define DD 128

#define ASHIFT 9            // bucket = dst >> 9 (512-node span)
#define NSPAN  512
#define BK     196          // ceil(100000/512)
#define BCAP   9216         // per-bucket capacity (mean 8192, sd ~90)
#define EPB    4096         // edges per phase-A block
#define NAB    391          // ceil(NE/EPB)

typedef __attribute__((ext_vector_type(8))) short bf16x8;
typedef __attribute__((ext_vector_type(4))) float f32x4;
typedef __attribute__((ext_vector_type(2))) float f32x2;

__device__ inline unsigned short f2bf(float f) {          // RNE float->bf16
    unsigned u = __builtin_bit_cast(unsigned, f);
    u += 0x7fff + ((u >> 16) & 1);
    return (unsigned short)(u >> 16);
}
__device__ inline float bf2f(unsigned short h) {
    return __builtin_bit_cast(float, (unsigned)h << 16);
}

// ---------------- phase A: bin edges into 196 buckets ----------------
// pairs entry: (local_dst << 17) | src   (src < 2^17, local < 2^9)
__global__ __launch_bounds__(256) void bucketA(const int* __restrict__ src,
                                               const int* __restrict__ dst,
                                               int* __restrict__ gcur,
                                               int* __restrict__ pairs) {
    __shared__ int hist[BK];
    __shared__ int gbase[BK];
    __shared__ int lcur[BK];
    const int t  = threadIdx.x;
    const int e0 = blockIdx.x * EPB;

    for (int i = t; i < BK; i += 256) hist[i] = 0;
    __syncthreads();
    for (int i = t; i < EPB; i += 256) {
        int e = e0 + i;
        if (e < NE) atomicAdd(&hist[dst[e] >> ASHIFT], 1);
    }
    __syncthreads();
    for (int i = t; i < BK; i += 256) {
        int c = hist[i];
        gbase[i] = i * BCAP + (c ? atomicAdd(&gcur[i], c) : 0);  // block-private run
        lcur[i] = 0;
    }
    __syncthreads();
    for (int i = t; i < EPB; i += 256) {
        int e = e0 + i;
        if (e < NE) {
            int d = dst[e];
            int b = d >> ASHIFT;
            int r = atomicAdd(&lcur[b], 1);
            pairs[gbase[b] + r] = ((d & (NSPAN - 1)) << 17) | src[e];
        }
    }
}

// ---------------- phase B: per-bucket CSR finalize (+cnt, +rowoff) --------
__global__ __launch_bounds__(256) void bucketB(const int* __restrict__ pairs,
                                               const int* __restrict__ gcur,
                                               int* __restrict__ cnt,
                                               int* __restrict__ rowoff,
                                               int* __restrict__ csr) {
    __shared__ int bs[256];
    __shared__ int hist[NSPAN];
    __shared__ int scanbuf[NSPAN];
    const int b = blockIdx.x, t = threadIdx.x;

    int v = (t < BK) ? gcur[t] : 0;
    bs[t] = v;
    __syncthreads();
    #pragma unroll
    for (int d = 1; d < 256; d <<= 1) {
        int u = (t >= d) ? bs[t - d] : 0;
        __syncthreads();
        bs[t] += u;
        __syncthreads();
    }
    const int sz   = gcur[b];
    const int base = bs[b] - sz;          // exclusive prefix

    const int n0    = b << ASHIFT;
    const int nodeN = min(NSPAN, NN - n0);
    const int* ep   = &pairs[(size_t)b * BCAP];

    for (int i = t; i < NSPAN; i += 256) hist[i] = 0;
    __syncthreads();
    for (int i = t; i < sz; i += 256) atomicAdd(&hist[((unsigned)ep[i]) >> 17], 1);
    __syncthreads();
    for (int i = t; i < nodeN; i += 256) cnt[n0 + i] = hist[i];
    for (int i = t; i < NSPAN; i += 256) scanbuf[i] = hist[i];
    __syncthreads();
    #pragma unroll
    for (int d = 1; d < NSPAN; d <<= 1) {
        int v0 = (t >= d) ? scanbuf[t - d] : 0;
        int v1 = (t + 256 >= d) ? scanbuf[t + 256 - d] : 0;
        __syncthreads();
        scanbuf[t] += v0;
        scanbuf[t + 256] += v1;
        __syncthreads();
    }
    for (int i = t; i < NSPAN; i += 256) {
        int excl = scanbuf[i] - hist[i];
        if (i < nodeN) rowoff[n0 + i] = base + excl;
        hist[i] = excl;                     // reuse as cursor
    }
    if (b == BK - 1 && t == 0) rowoff[NN] = NE;
    __syncthreads();
    for (int i = t; i < sz; i += 256) {
        int p = ep[i];
        int r = atomicAdd(&hist[((unsigned)p) >> 17], 1);
        csr[base + r] = p & 0x1FFFF;        // block-private ~32KB window
    }
}

// ---------------- fp32 -> bf16 + fp8 convert ----------------
__global__ __launch_bounds__(256) void tofeat_kernel(const float* __restrict__ in,
                                                     unsigned short* __restrict__ outb,
                                                     unsigned char* __restrict__ out8) {
    int i = blockIdx.x * 256 + threadIdx.x;   // one per 8 elements
    const float4 a = *(const float4*)&in[(size_t)i * 8];
    const float4 b = *(const float4*)&in[(size_t)i * 8 + 4];
    unsigned short o[8] = {f2bf(a.x), f2bf(a.y), f2bf(a.z), f2bf(a.w),
                           f2bf(b.x), f2bf(b.y), f2bf(b.z), f2bf(b.w)};
    *(bf16x8*)&outb[(size_t)i * 8] = *(bf16x8*)o;
    unsigned e0 = 0, e1 = 0;
    e0 = __builtin_amdgcn_cvt_pk_fp8_f32(a.x, a.y, e0, false);
    e0 = __builtin_amdgcn_cvt_pk_fp8_f32(a.z, a.w, e0, true);
    e1 = __builtin_amdgcn_cvt_pk_fp8_f32(b.x, b.y, e1, false);
    e1 = __builtin_amdgcn_cvt_pk_fp8_f32(b.z, b.w, e1, true);
    uint2 p = {e0, e1};
    *(uint2*)&out8[(size_t)i * 8] = p;
}

// ---------------- weight pre-conversion: fp32 -> bf16 fragment layout -----
// wsb layout: [layer(2)][half(2)][ko(16)][j(128)][e(8)] bf16
// one thread per (mat, ko, j); mat in {Wl1, Wr1, Wl2, Wr2}
__global__ __launch_bounds__(256) void prepw(const float* __restrict__ Wl1,
                                             const float* __restrict__ Wr1,
                                             const float* __restrict__ Wl2,
                                             const float* __restrict__ Wr2,
                                             unsigned short* __restrict__ wsb) {
    const int tid = blockIdx.x * 256 + threadIdx.x;   // 8192 total
    const int mat = tid >> 11;
    const int ko  = (tid >> 7) & 15;
    const int j   = tid & 127;
    const float* W = (mat == 0) ? Wl1 : (mat == 1) ? Wr1 : (mat == 2) ? Wl2 : Wr2;
    const float4 w0 = *(const float4*)&W[(size_t)j * DD + ko * 8];
    const float4 w1 = *(const float4*)&W[(size_t)j * DD + ko * 8 + 4];
    unsigned short o[8] = {f2bf(w0.x), f2bf(w0.y), f2bf(w0.z), f2bf(w0.w),
                           f2bf(w1.x), f2bf(w1.y), f2bf(w1.z), f2bf(w1.w)};
    *(bf16x8*)&wsb[(size_t)tid * 8] = *(bf16x8*)o;   // tid*8 == mat*16384 + (ko*128+j)*8
}

// ---------------- gather mean (fp8 in, bf16 out, fp32 accum) ----------------
// 16 lanes per node, 8 fp8 (8B) per lane; 4-edge unroll, 2 acc chains.
__device__ inline void accum8(float* a, uint2 u) {
    f32x2 p;
    p = __builtin_amdgcn_cvt_pk_f32_fp8(u.x, false); a[0] += p.x; a[1] += p.y;
    p = __builtin_amdgcn_cvt_pk_f32_fp8(u.x, true);  a[2] += p.x; a[3] += p.y;
    p = __builtin_amdgcn_cvt_pk_f32_fp8(u.y, false); a[4] += p.x; a[5] += p.y;
    p = __builtin_amdgcn_cvt_pk_f32_fp8(u.y, true);  a[6] += p.x; a[7] += p.y;
}

__global__ __launch_bounds__(256) void gather_fp8(const unsigned char* __restrict__ feat,
                                                  const int* __restrict__ rowoff,
                                                  const int* __restrict__ csr,
                                                  const int* __restrict__ cnt,
                                                  unsigned short* __restrict__ mean) {
    const int node = blockIdx.x * 16 + (threadIdx.x >> 4);
    const int l8 = (threadIdx.x & 15) * 8;
    const int beg = rowoff[node], end = rowoff[node + 1];
    float a0[8] = {0, 0, 0, 0, 0, 0, 0, 0};
    float a1[8] = {0, 0, 0, 0, 0, 0, 0, 0};
    int j = beg;
    for (; j + 3 < end; j += 4) {
        int s0 = csr[j], s1 = csr[j + 1], s2 = csr[j + 2], s3 = csr[j + 3];
        uint2 u0 = *(const uint2*)&feat[(size_t)s0 * DD + l8];
        uint2 u1 = *(const uint2*)&feat[(size_t)s1 * DD + l8];
        uint2 u2 = *(const uint2*)&feat[(size_t)s2 * DD + l8];
        uint2 u3 = *(const uint2*)&feat[(size_t)s3 * DD + l8];
        accum8(a0, u0); accum8(a1, u1); accum8(a0, u2); accum8(a1, u3);
    }
    for (; j < end; ++j) {
        int s0 = csr[j];
        uint2 u0 = *(const uint2*)&feat[(size_t)s0 * DD + l8];
        accum8(a0, u0);
    }
    const float inv = 1.0f / fmaxf((float)cnt[node], 1.0f);
    unsigned short o[8];
    #pragma unroll
    for (int i = 0; i < 8; ++i) o[i] = f2bf((a0[i] + a1[i]) * inv);
    *(bf16x8*)&mean[(size_t)node * DD + l8] = *(bf16x8*)o;
}

// ---------------- combine via MFMA: out = mean@Wl^T + self@Wr^T + b --------
// Wave-specialized, zero-LDS, software-pipelined:
//   - block = 4 waves on the SAME 16-row tile; wave w owns jt in {2w, 2w+1}
//   - B fragments register-resident (64 VGPR), loaded once from L2 wsb
//   - A-loads for tile t+1 issued BEFORE computing tile t (two named A/B
//     register sets, 2x-unrolled loop, static indexing) -> HBM latency of
//     the next tile hides under the current tile's 16 MFMAs + stores.
// VGPR audit: B 64 + A dbuf 64 + acc 8 + misc ~20 = ~158 < 170 cap of (256,3).
__global__ __launch_bounds__(256, 3) void combine_mfma(
    const unsigned short* __restrict__ mean, const unsigned short* __restrict__ self,
    const unsigned short* __restrict__ wsb,   // pre-converted bf16 fragments (64KB)
    const float* __restrict__ bias, void* __restrict__ outp,
    unsigned char* __restrict__ out8,         // optional fp8 copy (layer-1 h)
    int out_bf16, int do_relu)
{
    const int t = threadIdx.x;
    const int wv = t >> 6, lane = t & 63;
    const int m = lane & 15;
    const int q = lane >> 4;
    const int j0 = wv * 2;                    // this wave's jt pair

    // register-resident B fragments: [half][kq][jj]
    bf16x8 bfr[2][4][2];
    #pragma unroll
    for (int h = 0; h < 2; ++h)
        #pragma unroll
        for (int kq = 0; kq < 4; ++kq)
            #pragma unroll
            for (int jj = 0; jj < 2; ++jj)
                bfr[h][kq][jj] = *(const bf16x8*)
                    &wsb[((size_t)((h * 16 + kq * 4 + q) * 128) + (j0 + jj) * 16 + m) * 8];

    float bv[2];
    #pragma unroll
    for (int jj = 0; jj < 2; ++jj) bv[jj] = bias[(j0 + jj) * 16 + m];

    const int NT = NN / 16;
    const int stride = gridDim.x;

#define LOADA(AM, AS, TL)                                                     \
    {                                                                         \
        const size_t arow_ = ((size_t)(TL) * 16 + m) * DD + q * 8;            \
        _Pragma("unroll")                                                     \
        for (int kq = 0; kq < 4; ++kq) {                                      \
            AM[kq] = *(const bf16x8*)&mean[arow_ + kq * 32];                  \
            AS[kq] = *(const bf16x8*)&self[arow_ + kq * 32];                  \
        }                                                                     \
    }

#define COMPSTORE(AM, AS, TL)                                                 \
    {                                                                         \
        f32x4 acc0 = (f32x4){0.f, 0.f, 0.f, 0.f};                             \
        f32x4 acc1 = (f32x4){0.f, 0.f, 0.f, 0.f};                             \
        _Pragma("unroll")                                                     \
        for (int kq = 0; kq < 4; ++kq) {                                      \
            acc0 = __builtin_amdgcn_mfma_f32_16x16x32_bf16(AM[kq], bfr[0][kq][0], acc0, 0, 0, 0); \
            acc1 = __builtin_amdgcn_mfma_f32_16x16x32_bf16(AM[kq], bfr[0][kq][1], acc1, 0, 0, 0); \
            acc0 = __builtin_amdgcn_mfma_f32_16x16x32_bf16(AS[kq], bfr[1][kq][0], acc0, 0, 0, 0); \
            acc1 = __builtin_amdgcn_mfma_f32_16x16x32_bf16(AS[kq], bfr[1][kq][1], acc1, 0, 0, 0); \
        }                                                                     \
        _Pragma("unroll")                                                     \
        for (int jj = 0; jj < 2; ++jj) {                                      \
            const f32x4 accv = jj ? acc1 : acc0;                              \
            const int col = (j0 + jj) * 16 + m;                               \
            _Pragma("unroll")                                                 \
            for (int r = 0; r < 4; ++r) {                                     \
                const size_t row = (size_t)(TL) * 16 + q * 4 + r;             \
                float v = accv[r] + bv[jj];                                   \
                if (do_relu) v = fmaxf(v, 0.0f);                              \
                if (out_bf16)                                                 \
                    ((unsigned short*)outp)[row * DD + col] = f2bf(v);        \
                else                                                          \
                    ((float*)outp)[row * DD + col] = v;                       \
                if (out8) {                                                   \
                    unsigned p = __builtin_amdgcn_cvt_pk_fp8_f32(v, v, 0u, false); \
                    out8[row * DD + col] = (unsigned char)p;                  \
                }                                                             \
            }                                                                 \
        }                                                                     \
    }

    int tile = blockIdx.x;
    if (tile >= NT) return;

    bf16x8 amA[4], asA[4], amB[4], asB[4];
    LOADA(amA, asA, tile)

    while (true) {
        int nxt = tile + stride;
        if (nxt < NT) LOADA(amB, asB, nxt)          // prefetch t+1 before compute t
        COMPSTORE(amA, asA, tile)
        tile = nxt;
        if (tile >= NT) break;

        nxt = tile + stride;
        if (nxt < NT) LOADA(amA, asA, nxt)
        COMPSTORE(amB, asB, tile)
        tile = nxt;
        if (tile >= NT) break;
    }
#undef LOADA
#undef COMPSTORE
}

extern "C" void kernel_launch(void* const* d_in, const int* in_sizes, int n_in,
                              void* d_out, int out_size, void* d_ws, size_t ws_size,
                              hipStream_t stream) {
    const float* x   = (const float*)d_in[0];
    const int*   ei  = (const int*)d_in[1];
    const float* Wl1 = (const float*)d_in[2];
    const float* Wr1 = (const float*)d_in[3];
    const float* b1  = (const float*)d_in[4];
    const float* Wl2 = (const float*)d_in[5];
    const float* Wr2 = (const float*)d_in[6];
    const float* b2  = (const float*)d_in[7];
    const int* src = ei;
    const int* dst = ei + NE;
    float* out = (float*)d_out;

    // workspace layout
    unsigned short* xb   = (unsigned short*)d_ws;              // NN*DD bf16 (25.6MB)
    unsigned short* mean = xb + (size_t)NN * DD;               // NN*DD bf16 (25.6MB)
    unsigned short* h    = mean + (size_t)NN * DD;             // NN*DD bf16 (25.6MB)
    unsigned char*  x8   = (unsigned char*)(h + (size_t)NN * DD); // NN*DD fp8 (12.8MB)
    unsigned char*  h8   = x8 + (size_t)NN * DD;               // NN*DD fp8 (12.8MB)
    int*  pairs  = (int*)(h8 + (size_t)NN * DD);               // BK*BCAP (7.2MB)
    int*  gcur   = pairs + (size_t)BK * BCAP;                  // BK
    int*  cnt    = gcur + BK;                                  // NN
    int*  rowoff = cnt + NN;                                   // NN+1
    int*  csr    = rowoff + NN + 1;                            // NE (6.4MB)
    uintptr_t wp = ((uintptr_t)(csr + NE) + 255) & ~(uintptr_t)255;
    unsigned short* wsb = (unsigned short*)wp;                 // 2 layers * 32768 bf16 (128KB)

    hipMemsetAsync(gcur, 0, BK * sizeof(int), stream);
    prepw<<<32, 256, 0, stream>>>(Wl1, Wr1, Wl2, Wr2, wsb);
    bucketA<<<NAB, 256, 0, stream>>>(src, dst, gcur, pairs);
    bucketB<<<BK, 256, 0, stream>>>(pairs, gcur, cnt, rowoff, csr);

    tofeat_kernel<<<NN * DD / 8 / 256, 256, 0, stream>>>(x, xb, x8);

    gather_fp8<<<NN / 16, 256, 0, stream>>>(x8, rowoff, csr, cnt, mean);
    combine_mfma<<<2048, 256, 0, stream>>>(mean, xb, wsb, b1, h, h8, 1, 1);

    gather_fp8<<<NN / 16, 256, 0, stream>>>(h8, rowoff, csr, cnt, mean);
    combine_mfma<<<2048, 256, 0, stream>>>(mean, h, wsb + 32768, b2, out, nullptr, 0, 0);
}

// Round 5
// 308.822 us; speedup vs baseline: 1.1090x; 1.1090x over previous
//
#include <hip/hip_runtime.h>
#include <hip/hip_bf16.h>

#define NN 100000
#define NE 1600000
#define DD 128

#define ASHIFT 9            // bucket = dst >> 9 (512-node span)
#define NSPAN  512
#define BK     196          // ceil(100000/512)
#define BCAP   9216         // per-bucket capacity (mean 8192, sd ~90)
#define EPB    4096         // edges per phase-A block
#define NAB    391          // ceil(NE/EPB)

typedef __attribute__((ext_vector_type(8))) short bf16x8;
typedef __attribute__((ext_vector_type(4))) float f32x4;
typedef __attribute__((ext_vector_type(2))) float f32x2;

__device__ inline unsigned short f2bf(float f) {          // RNE float->bf16
    unsigned u = __builtin_bit_cast(unsigned, f);
    u += 0x7fff + ((u >> 16) & 1);
    return (unsigned short)(u >> 16);
}
__device__ inline float bf2f(unsigned short h) {
    return __builtin_bit_cast(float, (unsigned)h << 16);
}

// ---------------- phase A: bin edges into 196 buckets ----------------
// pairs entry: (local_dst << 17) | src   (src < 2^17, local < 2^9)
__global__ __launch_bounds__(256) void bucketA(const int* __restrict__ src,
                                               const int* __restrict__ dst,
                                               int* __restrict__ gcur,
                                               int* __restrict__ pairs) {
    __shared__ int hist[BK];
    __shared__ int gbase[BK];
    __shared__ int lcur[BK];
    const int t  = threadIdx.x;
    const int e0 = blockIdx.x * EPB;

    for (int i = t; i < BK; i += 256) hist[i] = 0;
    __syncthreads();
    for (int i = t; i < EPB; i += 256) {
        int e = e0 + i;
        if (e < NE) atomicAdd(&hist[dst[e] >> ASHIFT], 1);
    }
    __syncthreads();
    for (int i = t; i < BK; i += 256) {
        int c = hist[i];
        gbase[i] = i * BCAP + (c ? atomicAdd(&gcur[i], c) : 0);  // block-private run
        lcur[i] = 0;
    }
    __syncthreads();
    for (int i = t; i < EPB; i += 256) {
        int e = e0 + i;
        if (e < NE) {
            int d = dst[e];
            int b = d >> ASHIFT;
            int r = atomicAdd(&lcur[b], 1);
            pairs[gbase[b] + r] = ((d & (NSPAN - 1)) << 17) | src[e];
        }
    }
}

// ---------------- phase B: per-bucket CSR finalize (+cnt, +rowoff) --------
__global__ __launch_bounds__(256) void bucketB(const int* __restrict__ pairs,
                                               const int* __restrict__ gcur,
                                               int* __restrict__ cnt,
                                               int* __restrict__ rowoff,
                                               int* __restrict__ csr) {
    __shared__ int bs[256];
    __shared__ int hist[NSPAN];
    __shared__ int scanbuf[NSPAN];
    const int b = blockIdx.x, t = threadIdx.x;

    int v = (t < BK) ? gcur[t] : 0;
    bs[t] = v;
    __syncthreads();
    #pragma unroll
    for (int d = 1; d < 256; d <<= 1) {
        int u = (t >= d) ? bs[t - d] : 0;
        __syncthreads();
        bs[t] += u;
        __syncthreads();
    }
    const int sz   = gcur[b];
    const int base = bs[b] - sz;          // exclusive prefix

    const int n0    = b << ASHIFT;
    const int nodeN = min(NSPAN, NN - n0);
    const int* ep   = &pairs[(size_t)b * BCAP];

    for (int i = t; i < NSPAN; i += 256) hist[i] = 0;
    __syncthreads();
    for (int i = t; i < sz; i += 256) atomicAdd(&hist[((unsigned)ep[i]) >> 17], 1);
    __syncthreads();
    for (int i = t; i < nodeN; i += 256) cnt[n0 + i] = hist[i];
    for (int i = t; i < NSPAN; i += 256) scanbuf[i] = hist[i];
    __syncthreads();
    #pragma unroll
    for (int d = 1; d < NSPAN; d <<= 1) {
        int v0 = (t >= d) ? scanbuf[t - d] : 0;
        int v1 = (t + 256 >= d) ? scanbuf[t + 256 - d] : 0;
        __syncthreads();
        scanbuf[t] += v0;
        scanbuf[t + 256] += v1;
        __syncthreads();
    }
    for (int i = t; i < NSPAN; i += 256) {
        int excl = scanbuf[i] - hist[i];
        if (i < nodeN) rowoff[n0 + i] = base + excl;
        hist[i] = excl;                     // reuse as cursor
    }
    if (b == BK - 1 && t == 0) rowoff[NN] = NE;
    __syncthreads();
    for (int i = t; i < sz; i += 256) {
        int p = ep[i];
        int r = atomicAdd(&hist[((unsigned)p) >> 17], 1);
        csr[base + r] = p & 0x1FFFF;        // block-private ~32KB window
    }
}

// ---------------- fp32 -> bf16 + fp8 convert ----------------
__global__ __launch_bounds__(256) void tofeat_kernel(const float* __restrict__ in,
                                                     unsigned short* __restrict__ outb,
                                                     unsigned char* __restrict__ out8) {
    int i = blockIdx.x * 256 + threadIdx.x;   // one per 8 elements
    const float4 a = *(const float4*)&in[(size_t)i * 8];
    const float4 b = *(const float4*)&in[(size_t)i * 8 + 4];
    unsigned short o[8] = {f2bf(a.x), f2bf(a.y), f2bf(a.z), f2bf(a.w),
                           f2bf(b.x), f2bf(b.y), f2bf(b.z), f2bf(b.w)};
    *(bf16x8*)&outb[(size_t)i * 8] = *(bf16x8*)o;
    unsigned e0 = 0, e1 = 0;
    e0 = __builtin_amdgcn_cvt_pk_fp8_f32(a.x, a.y, e0, false);
    e0 = __builtin_amdgcn_cvt_pk_fp8_f32(a.z, a.w, e0, true);
    e1 = __builtin_amdgcn_cvt_pk_fp8_f32(b.x, b.y, e1, false);
    e1 = __builtin_amdgcn_cvt_pk_fp8_f32(b.z, b.w, e1, true);
    uint2 p = {e0, e1};
    *(uint2*)&out8[(size_t)i * 8] = p;
}

// ---------------- weight pre-conversion: fp32 -> bf16 fragment layout -----
// wsb layout: [layer(2)][half(2)][ko(16)][j(128)][e(8)] bf16
// one thread per (mat, ko, j); mat in {Wl1, Wr1, Wl2, Wr2}
__global__ __launch_bounds__(256) void prepw(const float* __restrict__ Wl1,
                                             const float* __restrict__ Wr1,
                                             const float* __restrict__ Wl2,
                                             const float* __restrict__ Wr2,
                                             unsigned short* __restrict__ wsb) {
    const int tid = blockIdx.x * 256 + threadIdx.x;   // 8192 total
    const int mat = tid >> 11;
    const int ko  = (tid >> 7) & 15;
    const int j   = tid & 127;
    const float* W = (mat == 0) ? Wl1 : (mat == 1) ? Wr1 : (mat == 2) ? Wl2 : Wr2;
    const float4 w0 = *(const float4*)&W[(size_t)j * DD + ko * 8];
    const float4 w1 = *(const float4*)&W[(size_t)j * DD + ko * 8 + 4];
    unsigned short o[8] = {f2bf(w0.x), f2bf(w0.y), f2bf(w0.z), f2bf(w0.w),
                           f2bf(w1.x), f2bf(w1.y), f2bf(w1.z), f2bf(w1.w)};
    *(bf16x8*)&wsb[(size_t)tid * 8] = *(bf16x8*)o;   // tid*8 == mat*16384 + (ko*128+j)*8
}

// ---------------- gather mean (fp8 in, bf16 out, fp32 accum) ----------------
// 16 lanes per node, 8 fp8 (8B) per lane; 8-edge unroll (8 loads in flight
// per lane to cover ~300-500cy L3 latency), 2 acc chains (parity split kept
// identical to the 4-unroll version -> bitwise-same output).
__device__ inline void accum8(float* a, uint2 u) {
    f32x2 p;
    p = __builtin_amdgcn_cvt_pk_f32_fp8(u.x, false); a[0] += p.x; a[1] += p.y;
    p = __builtin_amdgcn_cvt_pk_f32_fp8(u.x, true);  a[2] += p.x; a[3] += p.y;
    p = __builtin_amdgcn_cvt_pk_f32_fp8(u.y, false); a[4] += p.x; a[5] += p.y;
    p = __builtin_amdgcn_cvt_pk_f32_fp8(u.y, true);  a[6] += p.x; a[7] += p.y;
}

__global__ __launch_bounds__(256) void gather_fp8(const unsigned char* __restrict__ feat,
                                                  const int* __restrict__ rowoff,
                                                  const int* __restrict__ csr,
                                                  const int* __restrict__ cnt,
                                                  unsigned short* __restrict__ mean) {
    const int node = blockIdx.x * 16 + (threadIdx.x >> 4);
    const int l8 = (threadIdx.x & 15) * 8;
    const int beg = rowoff[node], end = rowoff[node + 1];
    float a0[8] = {0, 0, 0, 0, 0, 0, 0, 0};
    float a1[8] = {0, 0, 0, 0, 0, 0, 0, 0};
    int j = beg;
    for (; j + 7 < end; j += 8) {
        int s0 = csr[j],     s1 = csr[j + 1], s2 = csr[j + 2], s3 = csr[j + 3];
        int s4 = csr[j + 4], s5 = csr[j + 5], s6 = csr[j + 6], s7 = csr[j + 7];
        uint2 u0 = *(const uint2*)&feat[(size_t)s0 * DD + l8];
        uint2 u1 = *(const uint2*)&feat[(size_t)s1 * DD + l8];
        uint2 u2 = *(const uint2*)&feat[(size_t)s2 * DD + l8];
        uint2 u3 = *(const uint2*)&feat[(size_t)s3 * DD + l8];
        uint2 u4 = *(const uint2*)&feat[(size_t)s4 * DD + l8];
        uint2 u5 = *(const uint2*)&feat[(size_t)s5 * DD + l8];
        uint2 u6 = *(const uint2*)&feat[(size_t)s6 * DD + l8];
        uint2 u7 = *(const uint2*)&feat[(size_t)s7 * DD + l8];
        accum8(a0, u0); accum8(a1, u1); accum8(a0, u2); accum8(a1, u3);
        accum8(a0, u4); accum8(a1, u5); accum8(a0, u6); accum8(a1, u7);
    }
    for (; j + 3 < end; j += 4) {
        int s0 = csr[j], s1 = csr[j + 1], s2 = csr[j + 2], s3 = csr[j + 3];
        uint2 u0 = *(const uint2*)&feat[(size_t)s0 * DD + l8];
        uint2 u1 = *(const uint2*)&feat[(size_t)s1 * DD + l8];
        uint2 u2 = *(const uint2*)&feat[(size_t)s2 * DD + l8];
        uint2 u3 = *(const uint2*)&feat[(size_t)s3 * DD + l8];
        accum8(a0, u0); accum8(a1, u1); accum8(a0, u2); accum8(a1, u3);
    }
    for (; j < end; ++j) {
        int s0 = csr[j];
        uint2 u0 = *(const uint2*)&feat[(size_t)s0 * DD + l8];
        accum8(a0, u0);
    }
    const float inv = 1.0f / fmaxf((float)cnt[node], 1.0f);
    unsigned short o[8];
    #pragma unroll
    for (int i = 0; i < 8; ++i) o[i] = f2bf((a0[i] + a1[i]) * inv);
    *(bf16x8*)&mean[(size_t)node * DD + l8] = *(bf16x8*)o;
}

// ---------------- combine via MFMA: out = mean@Wl^T + self@Wr^T + b --------
// Wave-specialized, zero-LDS (round-3 known-good form):
//   - block = 4 waves; all 4 waves work on the SAME 16-row tile (L1-shared A)
//   - wave w owns output columns jt in {2w, 2w+1}
//   - its 16 B-fragments (64 VGPRs) are loaded ONCE from L2-resident wsb
// NOTE (round-4 post-mortem): do NOT manually software-pipeline the A loads —
// the allocator demotes the double-buffer arrays to scratch (+25MB spill
// traffic, 37->50us). The compiler already overlaps the 8 independent loads
// via fine-grained vmcnt within a tile.
__global__ __launch_bounds__(256, 3) void combine_mfma(
    const unsigned short* __restrict__ mean, const unsigned short* __restrict__ self,
    const unsigned short* __restrict__ wsb,   // pre-converted bf16 fragments (64KB)
    const float* __restrict__ bias, void* __restrict__ outp,
    unsigned char* __restrict__ out8,         // optional fp8 copy (layer-1 h)
    int out_bf16, int do_relu)
{
    const int t = threadIdx.x;
    const int wv = t >> 6, lane = t & 63;
    const int m = lane & 15;
    const int q = lane >> 4;
    const int j0 = wv * 2;                    // this wave's jt pair

    // register-resident B fragments: [half][kq][jj]
    bf16x8 bfr[2][4][2];
    #pragma unroll
    for (int h = 0; h < 2; ++h)
        #pragma unroll
        for (int kq = 0; kq < 4; ++kq)
            #pragma unroll
            for (int jj = 0; jj < 2; ++jj)
                bfr[h][kq][jj] = *(const bf16x8*)
                    &wsb[((size_t)((h * 16 + kq * 4 + q) * 128) + (j0 + jj) * 16 + m) * 8];

    float bv[2];
    #pragma unroll
    for (int jj = 0; jj < 2; ++jj) bv[jj] = bias[(j0 + jj) * 16 + m];

    for (int tile = blockIdx.x; tile < NN / 16; tile += gridDim.x) {
        const size_t arow = ((size_t)tile * 16 + m) * DD;
        f32x4 acc[2];
        acc[0] = (f32x4){0.f, 0.f, 0.f, 0.f};
        acc[1] = (f32x4){0.f, 0.f, 0.f, 0.f};

        #pragma unroll
        for (int kq = 0; kq < 4; ++kq) {
            const bf16x8 am = *(const bf16x8*)&mean[arow + kq * 32 + q * 8];
            const bf16x8 as = *(const bf16x8*)&self[arow + kq * 32 + q * 8];
            #pragma unroll
            for (int jj = 0; jj < 2; ++jj) {
                acc[jj] = __builtin_amdgcn_mfma_f32_16x16x32_bf16(am, bfr[0][kq][jj], acc[jj], 0, 0, 0);
                acc[jj] = __builtin_amdgcn_mfma_f32_16x16x32_bf16(as, bfr[1][kq][jj], acc[jj], 0, 0, 0);
            }
        }

        #pragma unroll
        for (int jj = 0; jj < 2; ++jj) {
            const int col = (j0 + jj) * 16 + m;
            #pragma unroll
            for (int r = 0; r < 4; ++r) {
                const size_t row = (size_t)tile * 16 + q * 4 + r;
                float v = acc[jj][r] + bv[jj];
                if (do_relu) v = fmaxf(v, 0.0f);
                if (out_bf16)
                    ((unsigned short*)outp)[row * DD + col] = f2bf(v);
                else
                    ((float*)outp)[row * DD + col] = v;
                if (out8) {
                    unsigned p = __builtin_amdgcn_cvt_pk_fp8_f32(v, v, 0u, false);
                    out8[row * DD + col] = (unsigned char)p;
                }
            }
        }
    }
}

extern "C" void kernel_launch(void* const* d_in, const int* in_sizes, int n_in,
                              void* d_out, int out_size, void* d_ws, size_t ws_size,
                              hipStream_t stream) {
    const float* x   = (const float*)d_in[0];
    const int*   ei  = (const int*)d_in[1];
    const float* Wl1 = (const float*)d_in[2];
    const float* Wr1 = (const float*)d_in[3];
    const float* b1  = (const float*)d_in[4];
    const float* Wl2 = (const float*)d_in[5];
    const float* Wr2 = (const float*)d_in[6];
    const float* b2  = (const float*)d_in[7];
    const int* src = ei;
    const int* dst = ei + NE;
    float* out = (float*)d_out;

    // workspace layout
    unsigned short* xb   = (unsigned short*)d_ws;              // NN*DD bf16 (25.6MB)
    unsigned short* mean = xb + (size_t)NN * DD;               // NN*DD bf16 (25.6MB)
    unsigned short* h    = mean + (size_t)NN * DD;             // NN*DD bf16 (25.6MB)
    unsigned char*  x8   = (unsigned char*)(h + (size_t)NN * DD); // NN*DD fp8 (12.8MB)
    unsigned char*  h8   = x8 + (size_t)NN * DD;               // NN*DD fp8 (12.8MB)
    int*  pairs  = (int*)(h8 + (size_t)NN * DD);               // BK*BCAP (7.2MB)
    int*  gcur   = pairs + (size_t)BK * BCAP;                  // BK
    int*  cnt    = gcur + BK;                                  // NN
    int*  rowoff = cnt + NN;                                   // NN+1
    int*  csr    = rowoff + NN + 1;                            // NE (6.4MB)
    uintptr_t wp = ((uintptr_t)(csr + NE) + 255) & ~(uintptr_t)255;
    unsigned short* wsb = (unsigned short*)wp;                 // 2 layers * 32768 bf16 (128KB)

    hipMemsetAsync(gcur, 0, BK * sizeof(int), stream);
    prepw<<<32, 256, 0, stream>>>(Wl1, Wr1, Wl2, Wr2, wsb);
    bucketA<<<NAB, 256, 0, stream>>>(src, dst, gcur, pairs);
    bucketB<<<BK, 256, 0, stream>>>(pairs, gcur, cnt, rowoff, csr);

    tofeat_kernel<<<NN * DD / 8 / 256, 256, 0, stream>>>(x, xb, x8);

    gather_fp8<<<NN / 16, 256, 0, stream>>>(x8, rowoff, csr, cnt, mean);
    combine_mfma<<<2048, 256, 0, stream>>>(mean, xb, wsb, b1, h, h8, 1, 1);

    gather_fp8<<<NN / 16, 256, 0, stream>>>(h8, rowoff, csr, cnt, mean);
    combine_mfma<<<2048, 256, 0, stream>>>(mean, h, wsb + 32768, b2, out, nullptr, 0, 0);
}

// Round 6
// 289.479 us; speedup vs baseline: 1.1831x; 1.0668x over previous
//
#include <hip/hip_runtime.h>
#include <hip/hip_bf16.h>

#define NN 100000
#define NE 1600000
#define DD 128

#define ASHIFT 8            // bucket = dst >> 8 (256-node span)
#define NSPAN  256
#define BK     391          // ceil(100000/256)
#define BCAP   4608         // per-bucket capacity (mean 4096, sd ~64 -> +8 sigma)
#define EPB    4096         // edges per phase-A block
#define NAB    391          // ceil(NE/EPB)
#define TFB    3125         // tofeat blocks: NN*DD/8/512

typedef __attribute__((ext_vector_type(8))) short bf16x8;
typedef __attribute__((ext_vector_type(4))) float f32x4;
typedef __attribute__((ext_vector_type(2))) float f32x2;

__device__ inline unsigned short f2bf(float f) {          // RNE float->bf16
    unsigned u = __builtin_bit_cast(unsigned, f);
    u += 0x7fff + ((u >> 16) & 1);
    return (unsigned short)(u >> 16);
}
__device__ inline float bf2f(unsigned short h) {
    return __builtin_bit_cast(float, (unsigned)h << 16);
}

// ---------------- fused phase A + tofeat ----------------
// blocks [0, NAB): bin edges into 391 buckets (LDS-atomic bound)
// blocks [NAB, NAB+TFB): fp32 -> bf16 + fp8 feature convert (BW bound)
// The two are independent and resource-complementary -> co-scheduled in one
// launch instead of serialized.
// pairs entry: (local_dst << 17) | src   (src < 2^17, local < 2^8)
__global__ __launch_bounds__(512) void fusedA(const int* __restrict__ src,
                                              const int* __restrict__ dst,
                                              int* __restrict__ gcur,
                                              int* __restrict__ pairs,
                                              const float* __restrict__ in,
                                              unsigned short* __restrict__ outb,
                                              unsigned char* __restrict__ out8) {
    __shared__ int hist[BK];
    __shared__ int gbase[BK];
    __shared__ int lcur[BK];
    const int t = threadIdx.x;

    if (blockIdx.x >= NAB) {
        // ---- tofeat part ----
        const size_t i = (size_t)(blockIdx.x - NAB) * 512 + t;   // one per 8 elems
        const float4 a = *(const float4*)&in[i * 8];
        const float4 b = *(const float4*)&in[i * 8 + 4];
        unsigned short o[8] = {f2bf(a.x), f2bf(a.y), f2bf(a.z), f2bf(a.w),
                               f2bf(b.x), f2bf(b.y), f2bf(b.z), f2bf(b.w)};
        *(bf16x8*)&outb[i * 8] = *(bf16x8*)o;
        unsigned e0 = 0, e1 = 0;
        e0 = __builtin_amdgcn_cvt_pk_fp8_f32(a.x, a.y, e0, false);
        e0 = __builtin_amdgcn_cvt_pk_fp8_f32(a.z, a.w, e0, true);
        e1 = __builtin_amdgcn_cvt_pk_fp8_f32(b.x, b.y, e1, false);
        e1 = __builtin_amdgcn_cvt_pk_fp8_f32(b.z, b.w, e1, true);
        uint2 p = {e0, e1};
        *(uint2*)&out8[i * 8] = p;
        return;
    }

    // ---- bucketA part ----
    const int e0 = blockIdx.x * EPB;

    for (int i = t; i < BK; i += 512) hist[i] = 0;
    __syncthreads();
    for (int i = t; i < EPB; i += 512) {
        int e = e0 + i;
        if (e < NE) atomicAdd(&hist[dst[e] >> ASHIFT], 1);
    }
    __syncthreads();
    for (int i = t; i < BK; i += 512) {
        int c = hist[i];
        gbase[i] = i * BCAP + (c ? atomicAdd(&gcur[i], c) : 0);  // block-private run
        lcur[i] = 0;
    }
    __syncthreads();
    for (int i = t; i < EPB; i += 512) {
        int e = e0 + i;
        if (e < NE) {
            int d = dst[e];
            int b = d >> ASHIFT;
            int r = atomicAdd(&lcur[b], 1);
            pairs[gbase[b] + r] = ((d & (NSPAN - 1)) << 17) | src[e];
        }
    }
}

// ---------------- phase B: per-bucket CSR finalize (+cnt, +rowoff) --------
// 512 threads (vs 256): halves the serial LDS-atomic iterations per thread
// and raises occupancy (391 blocks x 8 waves ~ 12 waves/CU vs 3 before).
__global__ __launch_bounds__(512) void bucketB(const int* __restrict__ pairs,
                                               const int* __restrict__ gcur,
                                               int* __restrict__ cnt,
                                               int* __restrict__ rowoff,
                                               int* __restrict__ csr) {
    __shared__ int bs[512];
    __shared__ int hist[NSPAN];
    __shared__ int scanbuf[NSPAN];
    const int b = blockIdx.x, t = threadIdx.x;

    int v = (t < BK) ? gcur[t] : 0;
    bs[t] = v;
    __syncthreads();
    #pragma unroll
    for (int d = 1; d < 512; d <<= 1) {
        int u = (t >= d) ? bs[t - d] : 0;
        __syncthreads();
        bs[t] += u;
        __syncthreads();
    }
    const int sz   = gcur[b];
    const int base = bs[b] - sz;          // exclusive prefix

    const int n0    = b << ASHIFT;
    const int nodeN = min(NSPAN, NN - n0);
    const int* ep   = &pairs[(size_t)b * BCAP];

    for (int i = t; i < NSPAN; i += 512) hist[i] = 0;
    __syncthreads();
    for (int i = t; i < sz; i += 512) atomicAdd(&hist[((unsigned)ep[i]) >> 17], 1);
    __syncthreads();
    for (int i = t; i < nodeN; i += 512) cnt[n0 + i] = hist[i];
    for (int i = t; i < NSPAN; i += 512) scanbuf[i] = hist[i];
    __syncthreads();
    #pragma unroll
    for (int d = 1; d < NSPAN; d <<= 1) {
        int v0 = (t >= d && t < NSPAN) ? scanbuf[t - d] : 0;
        __syncthreads();
        if (t < NSPAN) scanbuf[t] += v0;
        __syncthreads();
    }
    for (int i = t; i < NSPAN; i += 512) {
        int excl = scanbuf[i] - hist[i];
        if (i < nodeN) rowoff[n0 + i] = base + excl;
        hist[i] = excl;                     // reuse as cursor
    }
    if (b == BK - 1 && t == 0) rowoff[NN] = NE;
    __syncthreads();
    for (int i = t; i < sz; i += 512) {
        int p = ep[i];
        int r = atomicAdd(&hist[((unsigned)p) >> 17], 1);
        csr[base + r] = p & 0x1FFFF;        // block-private ~16KB window
    }
}

// ---------------- weight pre-conversion: fp32 -> bf16 fragment layout -----
// wsb layout: [layer(2)][half(2)][ko(16)][j(128)][e(8)] bf16
// one thread per (mat, ko, j); mat in {Wl1, Wr1, Wl2, Wr2}
__global__ __launch_bounds__(256) void prepw(const float* __restrict__ Wl1,
                                             const float* __restrict__ Wr1,
                                             const float* __restrict__ Wl2,
                                             const float* __restrict__ Wr2,
                                             unsigned short* __restrict__ wsb) {
    const int tid = blockIdx.x * 256 + threadIdx.x;   // 8192 total
    const int mat = tid >> 11;
    const int ko  = (tid >> 7) & 15;
    const int j   = tid & 127;
    const float* W = (mat == 0) ? Wl1 : (mat == 1) ? Wr1 : (mat == 2) ? Wl2 : Wr2;
    const float4 w0 = *(const float4*)&W[(size_t)j * DD + ko * 8];
    const float4 w1 = *(const float4*)&W[(size_t)j * DD + ko * 8 + 4];
    unsigned short o[8] = {f2bf(w0.x), f2bf(w0.y), f2bf(w0.z), f2bf(w0.w),
                           f2bf(w1.x), f2bf(w1.y), f2bf(w1.z), f2bf(w1.w)};
    *(bf16x8*)&wsb[(size_t)tid * 8] = *(bf16x8*)o;   // tid*8 == mat*16384 + (ko*128+j)*8
}

// ---------------- gather mean (fp8 in, bf16 out, fp32 accum) ----------------
// 16 lanes per node, 8 fp8 (8B) per lane; 8-edge unroll (8 loads in flight
// per lane to cover ~300-500cy L3 latency), 2 acc chains (parity split kept
// identical to the 4-unroll version -> bitwise-same output).
__device__ inline void accum8(float* a, uint2 u) {
    f32x2 p;
    p = __builtin_amdgcn_cvt_pk_f32_fp8(u.x, false); a[0] += p.x; a[1] += p.y;
    p = __builtin_amdgcn_cvt_pk_f32_fp8(u.x, true);  a[2] += p.x; a[3] += p.y;
    p = __builtin_amdgcn_cvt_pk_f32_fp8(u.y, false); a[4] += p.x; a[5] += p.y;
    p = __builtin_amdgcn_cvt_pk_f32_fp8(u.y, true);  a[6] += p.x; a[7] += p.y;
}

__global__ __launch_bounds__(256) void gather_fp8(const unsigned char* __restrict__ feat,
                                                  const int* __restrict__ rowoff,
                                                  const int* __restrict__ csr,
                                                  const int* __restrict__ cnt,
                                                  unsigned short* __restrict__ mean) {
    const int node = blockIdx.x * 16 + (threadIdx.x >> 4);
    const int l8 = (threadIdx.x & 15) * 8;
    const int beg = rowoff[node], end = rowoff[node + 1];
    float a0[8] = {0, 0, 0, 0, 0, 0, 0, 0};
    float a1[8] = {0, 0, 0, 0, 0, 0, 0, 0};
    int j = beg;
    for (; j + 7 < end; j += 8) {
        int s0 = csr[j],     s1 = csr[j + 1], s2 = csr[j + 2], s3 = csr[j + 3];
        int s4 = csr[j + 4], s5 = csr[j + 5], s6 = csr[j + 6], s7 = csr[j + 7];
        uint2 u0 = *(const uint2*)&feat[(size_t)s0 * DD + l8];
        uint2 u1 = *(const uint2*)&feat[(size_t)s1 * DD + l8];
        uint2 u2 = *(const uint2*)&feat[(size_t)s2 * DD + l8];
        uint2 u3 = *(const uint2*)&feat[(size_t)s3 * DD + l8];
        uint2 u4 = *(const uint2*)&feat[(size_t)s4 * DD + l8];
        uint2 u5 = *(const uint2*)&feat[(size_t)s5 * DD + l8];
        uint2 u6 = *(const uint2*)&feat[(size_t)s6 * DD + l8];
        uint2 u7 = *(const uint2*)&feat[(size_t)s7 * DD + l8];
        accum8(a0, u0); accum8(a1, u1); accum8(a0, u2); accum8(a1, u3);
        accum8(a0, u4); accum8(a1, u5); accum8(a0, u6); accum8(a1, u7);
    }
    for (; j + 3 < end; j += 4) {
        int s0 = csr[j], s1 = csr[j + 1], s2 = csr[j + 2], s3 = csr[j + 3];
        uint2 u0 = *(const uint2*)&feat[(size_t)s0 * DD + l8];
        uint2 u1 = *(const uint2*)&feat[(size_t)s1 * DD + l8];
        uint2 u2 = *(const uint2*)&feat[(size_t)s2 * DD + l8];
        uint2 u3 = *(const uint2*)&feat[(size_t)s3 * DD + l8];
        accum8(a0, u0); accum8(a1, u1); accum8(a0, u2); accum8(a1, u3);
    }
    for (; j < end; ++j) {
        int s0 = csr[j];
        uint2 u0 = *(const uint2*)&feat[(size_t)s0 * DD + l8];
        accum8(a0, u0);
    }
    const float inv = 1.0f / fmaxf((float)cnt[node], 1.0f);
    unsigned short o[8];
    #pragma unroll
    for (int i = 0; i < 8; ++i) o[i] = f2bf((a0[i] + a1[i]) * inv);
    *(bf16x8*)&mean[(size_t)node * DD + l8] = *(bf16x8*)o;
}

// ---------------- combine via MFMA: out = mean@Wl^T + self@Wr^T + b --------
// Wave-specialized, zero-LDS (round-3 known-good form):
//   - block = 4 waves; all 4 waves work on the SAME 16-row tile (L1-shared A)
//   - wave w owns output columns jt in {2w, 2w+1}
//   - its 16 B-fragments (64 VGPRs) are loaded ONCE from L2-resident wsb
// NOTE (round-4 post-mortem): do NOT manually software-pipeline the A loads —
// the allocator demotes the double-buffer arrays to scratch (+25MB spill
// traffic, 37->50us). The compiler already overlaps the 8 independent loads
// via fine-grained vmcnt within a tile.
__global__ __launch_bounds__(256, 3) void combine_mfma(
    const unsigned short* __restrict__ mean, const unsigned short* __restrict__ self,
    const unsigned short* __restrict__ wsb,   // pre-converted bf16 fragments (64KB)
    const float* __restrict__ bias, void* __restrict__ outp,
    unsigned char* __restrict__ out8,         // optional fp8 copy (layer-1 h)
    int out_bf16, int do_relu)
{
    const int t = threadIdx.x;
    const int wv = t >> 6, lane = t & 63;
    const int m = lane & 15;
    const int q = lane >> 4;
    const int j0 = wv * 2;                    // this wave's jt pair

    // register-resident B fragments: [half][kq][jj]
    bf16x8 bfr[2][4][2];
    #pragma unroll
    for (int h = 0; h < 2; ++h)
        #pragma unroll
        for (int kq = 0; kq < 4; ++kq)
            #pragma unroll
            for (int jj = 0; jj < 2; ++jj)
                bfr[h][kq][jj] = *(const bf16x8*)
                    &wsb[((size_t)((h * 16 + kq * 4 + q) * 128) + (j0 + jj) * 16 + m) * 8];

    float bv[2];
    #pragma unroll
    for (int jj = 0; jj < 2; ++jj) bv[jj] = bias[(j0 + jj) * 16 + m];

    for (int tile = blockIdx.x; tile < NN / 16; tile += gridDim.x) {
        const size_t arow = ((size_t)tile * 16 + m) * DD;
        f32x4 acc[2];
        acc[0] = (f32x4){0.f, 0.f, 0.f, 0.f};
        acc[1] = (f32x4){0.f, 0.f, 0.f, 0.f};

        #pragma unroll
        for (int kq = 0; kq < 4; ++kq) {
            const bf16x8 am = *(const bf16x8*)&mean[arow + kq * 32 + q * 8];
            const bf16x8 as = *(const bf16x8*)&self[arow + kq * 32 + q * 8];
            #pragma unroll
            for (int jj = 0; jj < 2; ++jj) {
                acc[jj] = __builtin_amdgcn_mfma_f32_16x16x32_bf16(am, bfr[0][kq][jj], acc[jj], 0, 0, 0);
                acc[jj] = __builtin_amdgcn_mfma_f32_16x16x32_bf16(as, bfr[1][kq][jj], acc[jj], 0, 0, 0);
            }
        }

        #pragma unroll
        for (int jj = 0; jj < 2; ++jj) {
            const int col = (j0 + jj) * 16 + m;
            #pragma unroll
            for (int r = 0; r < 4; ++r) {
                const size_t row = (size_t)tile * 16 + q * 4 + r;
                float v = acc[jj][r] + bv[jj];
                if (do_relu) v = fmaxf(v, 0.0f);
                if (out_bf16)
                    ((unsigned short*)outp)[row * DD + col] = f2bf(v);
                else
                    ((float*)outp)[row * DD + col] = v;
                if (out8) {
                    unsigned p = __builtin_amdgcn_cvt_pk_fp8_f32(v, v, 0u, false);
                    out8[row * DD + col] = (unsigned char)p;
                }
            }
        }
    }
}

extern "C" void kernel_launch(void* const* d_in, const int* in_sizes, int n_in,
                              void* d_out, int out_size, void* d_ws, size_t ws_size,
                              hipStream_t stream) {
    const float* x   = (const float*)d_in[0];
    const int*   ei  = (const int*)d_in[1];
    const float* Wl1 = (const float*)d_in[2];
    const float* Wr1 = (const float*)d_in[3];
    const float* b1  = (const float*)d_in[4];
    const float* Wl2 = (const float*)d_in[5];
    const float* Wr2 = (const float*)d_in[6];
    const float* b2  = (const float*)d_in[7];
    const int* src = ei;
    const int* dst = ei + NE;
    float* out = (float*)d_out;

    // workspace layout
    unsigned short* xb   = (unsigned short*)d_ws;              // NN*DD bf16 (25.6MB)
    unsigned short* mean = xb + (size_t)NN * DD;               // NN*DD bf16 (25.6MB)
    unsigned short* h    = mean + (size_t)NN * DD;             // NN*DD bf16 (25.6MB)
    unsigned char*  x8   = (unsigned char*)(h + (size_t)NN * DD); // NN*DD fp8 (12.8MB)
    unsigned char*  h8   = x8 + (size_t)NN * DD;               // NN*DD fp8 (12.8MB)
    int*  pairs  = (int*)(h8 + (size_t)NN * DD);               // BK*BCAP (7.2MB)
    int*  gcur   = pairs + (size_t)BK * BCAP;                  // BK
    int*  cnt    = gcur + BK;                                  // NN
    int*  rowoff = cnt + NN;                                   // NN+1
    int*  csr    = rowoff + NN + 1;                            // NE (6.4MB)
    uintptr_t wp = ((uintptr_t)(csr + NE) + 255) & ~(uintptr_t)255;
    unsigned short* wsb = (unsigned short*)wp;                 // 2 layers * 32768 bf16 (128KB)

    hipMemsetAsync(gcur, 0, BK * sizeof(int), stream);
    prepw<<<32, 256, 0, stream>>>(Wl1, Wr1, Wl2, Wr2, wsb);
    fusedA<<<NAB + TFB, 512, 0, stream>>>(src, dst, gcur, pairs, x, xb, x8);
    bucketB<<<BK, 512, 0, stream>>>(pairs, gcur, cnt, rowoff, csr);

    gather_fp8<<<NN / 16, 256, 0, stream>>>(x8, rowoff, csr, cnt, mean);
    combine_mfma<<<2048, 256, 0, stream>>>(mean, xb, wsb, b1, h, h8, 1, 1);

    gather_fp8<<<NN / 16, 256, 0, stream>>>(h8, rowoff, csr, cnt, mean);
    combine_mfma<<<2048, 256, 0, stream>>>(mean, h, wsb + 32768, b2, out, nullptr, 0, 0);
}